// Round 10
// baseline (244.014 us; speedup 1.0000x reference)
//
#include <hip/hip_runtime.h>
#include <hip/hip_bf16.h>
#include <math.h>

#define NB 64      // batch
#define NN 576     // patches
#define ND 512     // dim
#define NM 16      // nouns
#define QPB 9      // quads per batch element (64 patches each)
#define KPOS 5
#define TINV 14.2857142857142857f   // 1/0.07

#define NFINE (NB * QPB)            // 576 fine blocks
#define NBLK1 (NFINE + NB)          // 640
#define WS_REC_OFF 4096             // records after 64x64 scores
#define RECSZ 144                   // floats per fine-block record
#define WS_NOUNF (WS_REC_OFF + NFINE * RECSZ)     // 87040 (bf16 noun: 262144 floats)
#define CNT_IDX (WS_NOUNF + 262144)               // 349184: completion counter

#define FINF __builtin_inff()

typedef __attribute__((ext_vector_type(8))) short short8;   // 8 bf16 (4 VGPRs)
typedef __attribute__((ext_vector_type(4))) float floatx4;  // MFMA C/D

// pack two fp32 into one dword of 2 bf16 by TRUNCATION: single v_perm_b32
__device__ __forceinline__ unsigned pk2(float lo, float hi) {
  return __builtin_amdgcn_perm(__float_as_uint(hi), __float_as_uint(lo), 0x07060302u);
}

__device__ __forceinline__ short8 packB(const float4 a, const float4 b) {
  union { unsigned u[4]; short8 s; } cv;
  cv.u[0] = pk2(a.x, a.y);
  cv.u[1] = pk2(a.z, a.w);
  cv.u[2] = pk2(b.x, b.y);
  cv.u[3] = pk2(b.z, b.w);
  return cv.s;
}

// insert v into desc-sorted 5-list (constant indices only -> stays in VGPRs)
__device__ __forceinline__ void ins5(float (&a)[5], float v) {
  if (v > a[4]) {
    a[4] = v;
    if (a[4] > a[3]) { float x = a[4]; a[4] = a[3]; a[3] = x; }
    if (a[3] > a[2]) { float x = a[3]; a[3] = a[2]; a[2] = x; }
    if (a[2] > a[1]) { float x = a[2]; a[2] = a[1]; a[1] = x; }
    if (a[1] > a[0]) { float x = a[1]; a[1] = a[0]; a[0] = x; }
  }
}

// top-5 of union of two desc-sorted 5-lists, branch-free fixed-index rank merge
__device__ __forceinline__ void merge5(float (&a)[5], const float (&b)[5]) {
  float r[5];
#pragma unroll
  for (int k = 0; k < 5; ++k) {
    float best = -FINF;
#pragma unroll
    for (int i = 0; i <= k + 1; ++i) {
      const int j = k + 1 - i;
      const float av = (i == 0) ? FINF : a[i - 1];
      const float bv = (j == 0) ? FINF : b[j - 1];
      best = fmaxf(best, fminf(av, bv));
    }
    r[k] = best;
  }
#pragma unroll
  for (int k = 0; k < 5; ++k) a[k] = r[k];
}

__device__ __forceinline__ void merge5_shfl(float (&a)[5], int msk) {
  float o[5];
#pragma unroll
  for (int k = 0; k < 5; ++k) o[k] = __shfl_xor(a[k], msk, 64);
  merge5(a, o);
}

// ============ kernel 0: noun fp32 -> bf16 (RNE; done once, reused 36x) ============
__global__ __launch_bounds__(256) void k_prep(
    const float* __restrict__ noun, float* __restrict__ ws) {
  const int i = blockIdx.x * 256 + threadIdx.x;   // 131072 threads x 4 floats
  const float4 v = ((const float4*)noun)[i];
  unsigned ux = __float_as_uint(v.x), uy = __float_as_uint(v.y);
  unsigned uz = __float_as_uint(v.z), uw = __float_as_uint(v.w);
  ux += 0x7FFFu + ((ux >> 16) & 1u);
  uy += 0x7FFFu + ((uy >> 16) & 1u);
  uz += 0x7FFFu + ((uz >> 16) & 1u);
  uw += 0x7FFFu + ((uw >> 16) & 1u);
  uint2 o;
  o.x = __builtin_amdgcn_perm(uy, ux, 0x07060302u);
  o.y = __builtin_amdgcn_perm(uw, uz, 0x07060302u);
  ((uint2*)((unsigned short*)(ws + WS_NOUNF)))[i] = o;
}

// ============ kernel 1: MFMA sim tiles + partial records + scores + fused finale ====
__global__ __launch_bounds__(256) void k_sim(
    const float* __restrict__ patch, const float* __restrict__ gimg,
    const float* __restrict__ gtxt, const float* __restrict__ lscale,
    const int* __restrict__ idx, float* __restrict__ ws,
    float* __restrict__ out) {
  const int blk = blockIdx.x;
  const int t = threadIdx.x;
  const int lane = t & 63;
  const int w = t >> 6;

  __shared__ float S[4288];   // fine: 1040 / score: 256 / finale: 64x65+dg+idl
  __shared__ unsigned int winflag;

  if (blk < NFINE) {
    // ---- fine block (b, quad): wave w = 16-noun x 16-patch full-K C-tile ----
    const int b = blk / QPB, quad = blk - b * QPB;
    const int nidx = lane & 15;          // A: noun row m / B: patch col n
    const int k0 = (lane >> 4) * 8;      // k-offset within 32-wide kstep

    const unsigned short* nrow =
        (const unsigned short*)(ws + WS_NOUNF) + ((size_t)b * NM + nidx) * ND + k0;
    const float* prow =
        patch + ((size_t)(b * NN + quad * 64 + w * 16 + nidx)) * ND + k0;

    floatx4 acc = {0.f, 0.f, 0.f, 0.f};
#pragma unroll 4
    for (int ks = 0; ks < 16; ++ks) {
      const int o = ks * 32;
      const short8 af = *(const short8*)(nrow + o);
      const float4 p0 = *(const float4*)(prow + o);
      const float4 p1 = *(const float4*)(prow + o + 4);
      const short8 bf = packB(p0, p1);
      acc = __builtin_amdgcn_mfma_f32_16x16x32_bf16(af, bf, acc, 0, 0, 0);
    }

    // C/D layout: col(=patch)=lane&15, row(=noun)=(lane>>4)*4+r  [m89-verified]
    const int mrow = (lane >> 4) * 4;
    const int pcol = w * 16 + nidx;
#pragma unroll
    for (int r = 0; r < 4; ++r) S[(mrow + r) * 65 + pcol] = acc[r] * TINV;
    __syncthreads();

    float* rec = ws + WS_REC_OFF + (size_t)blk * RECSZ;
    if (w == 1) {
      // ---- mask partials: softplus sum + top5 of pooled/T over 64 patches ----
      float x = 0.f;
#pragma unroll
      for (int m = 0; m < NM; ++m) x += S[m * 65 + lane];
      x *= (1.f / 16.f);
      float sxp = (x > 0.f) ? (x + log1pf(expf(-x))) : log1pf(expf(x));
      float t5[5] = {x, -FINF, -FINF, -FINF, -FINF};
#pragma unroll
      for (int msk = 1; msk < 64; msk <<= 1) {
        sxp += __shfl_xor(sxp, msk, 64);
        merge5_shfl(t5, msk);
      }
      if (lane == 0) {
        rec[128] = sxp;
#pragma unroll
        for (int k = 0; k < 5; ++k) rec[129 + k] = t5[k];
      }
    } else if (w == 0) {
      // ---- per-noun row stats over 64 cols (16 rows x 4 segments) ----
      const int r_ = lane & 15;
      const int h = lane >> 4;
      const float* row = &S[r_ * 65 + h * 16];
      float mx = -FINF;
#pragma unroll
      for (int k = 0; k < 16; ++k) mx = fmaxf(mx, row[k]);
      mx = fmaxf(mx, __shfl_xor(mx, 16, 64));
      mx = fmaxf(mx, __shfl_xor(mx, 32, 64));
      float se = 0.f;
      float r5[5] = {-FINF, -FINF, -FINF, -FINF, -FINF};
#pragma unroll
      for (int k = 0; k < 16; ++k) {
        const float v = row[k];
        se += expf(v - mx);
        ins5(r5, v);
      }
      se += __shfl_xor(se, 16, 64);
      se += __shfl_xor(se, 32, 64);
      merge5_shfl(r5, 16);
      merge5_shfl(r5, 32);
      if (h == 0) {
        float* rr = rec + r_ * 8;
        rr[0] = mx;
        rr[1] = se;
#pragma unroll
        for (int k = 0; k < 5; ++k) rr[2 + k] = r5[k];
      }
    }
  } else {
    // ---- score block: scores[i][j] = <img_i, txt_j> ----
    const int i = blk - NFINE;
    const float4* ip = (const float4*)(gimg + (size_t)i * ND + w * 128);
    const float4* tp = (const float4*)(gtxt + (size_t)lane * ND + w * 128);
    float a = 0.f;
#pragma unroll
    for (int q = 0; q < 32; ++q) {
      const float4 x = ip[q];
      const float4 y = tp[q];
      a += x.x * y.x + x.y * y.y + x.z * y.z + x.w * y.w;
    }
    S[w * 64 + lane] = a;
    __syncthreads();
    if (t < 64) ws[i * 64 + t] = S[t] + S[64 + t] + S[128 + t] + S[192 + t];
  }

  // ========== completion counter; last block runs the finale ==========
  __syncthreads();
  __threadfence();                       // release this block's ws writes
  if (t == 0) {
    const unsigned old = atomicAdd((unsigned int*)(ws + CNT_IDX), 1u);
    winflag = (old == NBLK1 - 1) ? 1u : 0u;
  }
  __syncthreads();
  if (!winflag) return;
  __threadfence();                       // acquire: see all other blocks' writes

  // ---- Part A: contrastive merge over 1024 (b,m) pairs ----
  const float* recs = ws + WS_REC_OFF;
  float local = 0.f;
  for (int i = t; i < NB * NM; i += 256) {
    const int b = i >> 4, m = i & 15;
    const float* base = recs + (size_t)b * QPB * RECSZ + m * 8;
    float mx = -FINF;
#pragma unroll
    for (int q = 0; q < QPB; ++q) mx = fmaxf(mx, base[q * RECSZ]);
    float S5 = 0.f;
    float t5[5] = {-FINF, -FINF, -FINF, -FINF, -FINF};
#pragma unroll
    for (int q = 0; q < QPB; ++q) {
      S5 += base[q * RECSZ + 1] * expf(base[q * RECSZ] - mx);
#pragma unroll
      for (int k = 0; k < 5; ++k) ins5(t5, base[q * RECSZ + 2 + k]);
    }
    const float st = t5[0] + t5[1] + t5[2] + t5[3] + t5[4];
    local += (KPOS * (mx + logf(S5)) - st) * (0.6f / (float)(NB * NM));
  }
  // ---- Part B: mask merge per b (threads 0..63) ----
  if (t < NB) {
    const float* base = recs + (size_t)t * QPB * RECSZ + 128;
    float sp = 0.f;
    float u5[5] = {-FINF, -FINF, -FINF, -FINF, -FINF};
#pragma unroll
    for (int q = 0; q < QPB; ++q) {
      sp += base[q * RECSZ];
#pragma unroll
      for (int k = 0; k < 5; ++k) ins5(u5, base[q * RECSZ + 1 + k]);
    }
    const float st = u5[0] + u5[1] + u5[2] + u5[3] + u5[4];
    local += (sp - st) * (0.4f / (float)(NB * NN));
  }
#pragma unroll
  for (int msk = 1; msk < 64; msk <<= 1) local += __shfl_xor(local, msk, 64);
  __syncthreads();                       // S free for reuse
  if (lane == 0) S[w] = local;
  __syncthreads();
  if (t == 0) out[2] = S[0] + S[1] + S[2] + S[3];
  __syncthreads();

  // ---- Part C: loss_c (CLIP bi-directional CE) + loss_t (triplet) ----
  float* S_ = &S[0];                     // 64 x 65 padded score tile
  for (int i = t; i < 4096; i += 256) S_[(i >> 6) * 65 + (i & 63)] = ws[i];
  __syncthreads();
  float* dgp = &S[4160];
  int* idl = (int*)&S[4224];
  if (t < 64) { dgp[t] = S_[t * 66]; idl[t] = idx[t]; }
  __syncthreads();
  if (t < 64) {                          // exactly wave 0
    const float sc = lscale[0];
    float mR = -FINF, mC = -FINF;
    for (int j = 0; j < 64; ++j) {
      mR = fmaxf(mR, sc * S_[t * 65 + j]);
      mC = fmaxf(mC, sc * S_[j * 65 + t]);
    }
    float seR = 0.f, seC = 0.f;
    for (int j = 0; j < 64; ++j) {
      seR += expf(sc * S_[t * 65 + j] - mR);
      seC += expf(sc * S_[j * 65 + t] - mC);
    }
    const float lseR = mR + logf(seR);
    const float lseC = mC + logf(seC);
    const int myid = idl[t];
    const float di = dgp[t];
    float ps = 0.f, trow = 0.f, tcol = 0.f, cs = 0.f, ci = 0.f;
    for (int j = 0; j < 64; ++j) {
      const float sv = S_[t * 65 + j];
      const float svT = S_[j * 65 + t];
      if (idl[j] == myid) {
        ps += 1.f;
        trow += sc * sv - lseR;
        tcol += sc * svT - lseC;
      }
      if (j != t) {
        cs += fmaxf(0.f, 0.1f + sv - di);
        ci += fmaxf(0.f, 0.1f + sv - dgp[j]);
      }
    }
    float vc = -(trow + tcol) / ps;
    float vt = cs + ci;
#pragma unroll
    for (int msk = 1; msk < 64; msk <<= 1) {
      vc += __shfl_xor(vc, msk, 64);
      vt += __shfl_xor(vt, msk, 64);
    }
    if (t == 0) {
      out[0] = vc * (0.5f / 64.f);
      out[1] = vt * 0.5f;
    }
  }
}

extern "C" void kernel_launch(void* const* d_in, const int* in_sizes, int n_in,
                              void* d_out, int out_size, void* d_ws, size_t ws_size,
                              hipStream_t stream) {
  const float* patch = (const float*)d_in[0];
  const float* noun  = (const float*)d_in[1];
  const float* gimg  = (const float*)d_in[2];
  const float* gtxt  = (const float*)d_in[3];
  const float* lsc   = (const float*)d_in[4];
  const int*   idx   = (const int*)d_in[5];
  float* out = (float*)d_out;
  float* ws  = (float*)d_ws;

  // zero only the completion counter (ws is poisoned 0xAA each launch);
  // out[0..2] are plain-stored by the winner block -- no d_out memset needed.
  hipMemsetAsync((char*)d_ws + (size_t)CNT_IDX * sizeof(float), 0, 4, stream);
  k_prep<<<dim3(512), dim3(256), 0, stream>>>(noun, ws);
  k_sim<<<dim3(NBLK1), dim3(256), 0, stream>>>(patch, gimg, gtxt, lsc, idx, ws, out);
}

// Round 11
// 138.569 us; speedup vs baseline: 1.7610x; 1.7610x over previous
//
#include <hip/hip_runtime.h>
#include <hip/hip_bf16.h>
#include <math.h>

#define NB 64      // batch
#define NN 576     // patches
#define ND 512     // dim
#define NM 16      // nouns
#define QPB 9      // quads per batch element (64 patches each)
#define KPOS 5
#define TINV 14.2857142857142857f   // 1/0.07

#define NFINE (NB * QPB)            // 576 fine blocks
#define NBLK1 (NFINE + NB)          // 640
#define WS_REC_OFF 4096             // records after 64x64 scores
#define RECSZ 144                   // floats per fine-block record

#define FINF __builtin_inff()

typedef __attribute__((ext_vector_type(8))) short short8;   // 8 bf16 (4 VGPRs)
typedef __attribute__((ext_vector_type(4))) float floatx4;  // MFMA C/D

// pack two fp32 into one dword of 2 bf16 by TRUNCATION: single v_perm_b32
__device__ __forceinline__ unsigned pk2(float lo, float hi) {
  return __builtin_amdgcn_perm(__float_as_uint(hi), __float_as_uint(lo), 0x07060302u);
}

__device__ __forceinline__ short8 packB(const float4 a, const float4 b) {
  union { unsigned u[4]; short8 s; } cv;
  cv.u[0] = pk2(a.x, a.y);
  cv.u[1] = pk2(a.z, a.w);
  cv.u[2] = pk2(b.x, b.y);
  cv.u[3] = pk2(b.z, b.w);
  return cv.s;
}

// insert v into desc-sorted 5-list (constant indices only -> stays in VGPRs)
__device__ __forceinline__ void ins5(float (&a)[5], float v) {
  if (v > a[4]) {
    a[4] = v;
    if (a[4] > a[3]) { float x = a[4]; a[4] = a[3]; a[3] = x; }
    if (a[3] > a[2]) { float x = a[3]; a[3] = a[2]; a[2] = x; }
    if (a[2] > a[1]) { float x = a[2]; a[2] = a[1]; a[1] = x; }
    if (a[1] > a[0]) { float x = a[1]; a[1] = a[0]; a[0] = x; }
  }
}

// top-5 of union of two desc-sorted 5-lists, branch-free fixed-index rank merge
__device__ __forceinline__ void merge5(float (&a)[5], const float (&b)[5]) {
  float r[5];
#pragma unroll
  for (int k = 0; k < 5; ++k) {
    float best = -FINF;
#pragma unroll
    for (int i = 0; i <= k + 1; ++i) {
      const int j = k + 1 - i;
      const float av = (i == 0) ? FINF : a[i - 1];
      const float bv = (j == 0) ? FINF : b[j - 1];
      best = fmaxf(best, fminf(av, bv));
    }
    r[k] = best;
  }
#pragma unroll
  for (int k = 0; k < 5; ++k) a[k] = r[k];
}

__device__ __forceinline__ void merge5_shfl(float (&a)[5], int msk) {
  float o[5];
#pragma unroll
  for (int k = 0; k < 5; ++k) o[k] = __shfl_xor(a[k], msk, 64);
  merge5(a, o);
}

// ============ kernel 1: MFMA sim tile + per-quad partial records + scores ============
// fine block (b, quad): wave w computes the 16-noun x 16-patch full-K C-tile
// for patches quad*64 + w*16..+15. Both fragments loaded straight from global
// fp32 and packed to bf16 with v_perm truncation (noun conversion inlined --
// no k_prep dispatch; dispatches cost ~dozens of µs on this harness).
// NO device-scope fences here (R10: fence-per-block cost ~140 µs).
__global__ __launch_bounds__(256) void k_sim(
    const float* __restrict__ patch, const float* __restrict__ noun,
    const float* __restrict__ gimg, const float* __restrict__ gtxt,
    float* __restrict__ ws) {
  const int blk = blockIdx.x;
  const int t = threadIdx.x;
  const int lane = t & 63;
  const int w = t >> 6;

  __shared__ float S[NM * 65];   // 4160 B: scaled sim tile (score path reuses head)

  if (blk < NFINE) {
    const int b = blk / QPB, quad = blk - b * QPB;
    const int nidx = lane & 15;          // A: noun row m / B: patch col n
    const int k0 = (lane >> 4) * 8;      // k-offset within 32-wide kstep

    const float* nrow = noun + ((size_t)b * NM + nidx) * ND + k0;
    const float* prow =
        patch + ((size_t)(b * NN + quad * 64 + w * 16 + nidx)) * ND + k0;

    floatx4 acc = {0.f, 0.f, 0.f, 0.f};
#pragma unroll 4
    for (int ks = 0; ks < 16; ++ks) {
      const int o = ks * 32;
      const float4 a0 = *(const float4*)(nrow + o);
      const float4 a1 = *(const float4*)(nrow + o + 4);
      const float4 p0 = *(const float4*)(prow + o);
      const float4 p1 = *(const float4*)(prow + o + 4);
      const short8 af = packB(a0, a1);
      const short8 bf = packB(p0, p1);
      acc = __builtin_amdgcn_mfma_f32_16x16x32_bf16(af, bf, acc, 0, 0, 0);
    }

    // C/D layout: col(=patch)=lane&15, row(=noun)=(lane>>4)*4+r  [m89-verified]
    const int mrow = (lane >> 4) * 4;
    const int pcol = w * 16 + nidx;
#pragma unroll
    for (int r = 0; r < 4; ++r) S[(mrow + r) * 65 + pcol] = acc[r] * TINV;
    __syncthreads();

    float* rec = ws + WS_REC_OFF + (size_t)blk * RECSZ;
    if (w == 1) {
      // ---- mask partials: softplus sum + top5 of pooled/T over 64 patches ----
      float x = 0.f;
#pragma unroll
      for (int m = 0; m < NM; ++m) x += S[m * 65 + lane];
      x *= (1.f / 16.f);
      float sxp = (x > 0.f) ? (x + log1pf(expf(-x))) : log1pf(expf(x));
      float t5[5] = {x, -FINF, -FINF, -FINF, -FINF};
#pragma unroll
      for (int msk = 1; msk < 64; msk <<= 1) {
        sxp += __shfl_xor(sxp, msk, 64);
        merge5_shfl(t5, msk);
      }
      if (lane == 0) {
        rec[128] = sxp;
#pragma unroll
        for (int k = 0; k < 5; ++k) rec[129 + k] = t5[k];
      }
    } else if (w == 0) {
      // ---- per-noun row stats over 64 cols (16 rows x 4 segments) ----
      const int r_ = lane & 15;
      const int h = lane >> 4;
      const float* row = &S[r_ * 65 + h * 16];
      float mx = -FINF;
#pragma unroll
      for (int k = 0; k < 16; ++k) mx = fmaxf(mx, row[k]);
      mx = fmaxf(mx, __shfl_xor(mx, 16, 64));
      mx = fmaxf(mx, __shfl_xor(mx, 32, 64));
      float se = 0.f;
      float r5[5] = {-FINF, -FINF, -FINF, -FINF, -FINF};
#pragma unroll
      for (int k = 0; k < 16; ++k) {
        const float v = row[k];
        se += expf(v - mx);
        ins5(r5, v);
      }
      se += __shfl_xor(se, 16, 64);
      se += __shfl_xor(se, 32, 64);
      merge5_shfl(r5, 16);
      merge5_shfl(r5, 32);
      if (h == 0) {
        float* rr = rec + r_ * 8;
        rr[0] = mx;
        rr[1] = se;
#pragma unroll
        for (int k = 0; k < 5; ++k) rr[2 + k] = r5[k];
      }
    }
  } else {
    // score block: scores[i][j] = <img_i, txt_j>
    const int i = blk - NFINE;
    const float4* ip = (const float4*)(gimg + (size_t)i * ND + w * 128);
    const float4* tp = (const float4*)(gtxt + (size_t)lane * ND + w * 128);
    float a = 0.f;
#pragma unroll
    for (int q = 0; q < 32; ++q) {
      const float4 x = ip[q];
      const float4 y = tp[q];
      a += x.x * y.x + x.y * y.y + x.z * y.z + x.w * y.w;
    }
    S[w * 64 + lane] = a;
    __syncthreads();
    if (t < 64) ws[i * 64 + t] = S[t] + S[64 + t] + S[128 + t] + S[192 + t];
  }
}

// ============ kernel 2: merge records + CLIP/triplet (R9-verified) ============
__global__ __launch_bounds__(64) void k_final(
    const float* __restrict__ ws, const float* __restrict__ lscale,
    const int* __restrict__ idx, float* __restrict__ out) {
  const int blk = blockIdx.x;
  const int t = threadIdx.x;

  if (blk < NB) {
    // ---- merge the 9 quad partials for batch element blk (lane-parallel) ----
    const float* base = ws + WS_REC_OFF + (size_t)blk * QPB * RECSZ;
    const int m = t & 15;
    const int g = t >> 4;               // quad group: g gets quads {g, g+4, (g==0: 8)}
    const int nq = (g == 0) ? 3 : 2;

    float lm[3], ls[3];
    float t5[5] = {-FINF, -FINF, -FINF, -FINF, -FINF};
#pragma unroll
    for (int i = 0; i < 3; ++i) { lm[i] = -FINF; ls[i] = 0.f; }
    float mx = -FINF;
    for (int i = 0; i < nq; ++i) {
      const float* rr = base + (g + 4 * i) * RECSZ + m * 8;
      lm[i] = rr[0]; ls[i] = rr[1];
      mx = fmaxf(mx, rr[0]);
#pragma unroll
      for (int k = 0; k < 5; ++k) ins5(t5, rr[2 + k]);
    }
    mx = fmaxf(mx, __shfl_xor(mx, 16, 64));
    mx = fmaxf(mx, __shfl_xor(mx, 32, 64));
    float S = 0.f;
    for (int i = 0; i < nq; ++i) S += ls[i] * expf(lm[i] - mx);
    S += __shfl_xor(S, 16, 64);
    S += __shfl_xor(S, 32, 64);
    merge5_shfl(t5, 16);
    merge5_shfl(t5, 32);

    float contrib = 0.f;
    if (g == 0) {
      const float lse = mx + logf(S);
      const float st = t5[0] + t5[1] + t5[2] + t5[3] + t5[4];
      contrib = (KPOS * lse - st) * (0.6f / (float)(NB * NM));
    }

    // mask partials on lanes with m==0 (g-split over quads, reduce across g)
    float sp_ = 0.f;
    float u5[5] = {-FINF, -FINF, -FINF, -FINF, -FINF};
    if (m == 0) {
      for (int i = 0; i < nq; ++i) {
        const float* rr = base + (g + 4 * i) * RECSZ + 128;
        sp_ += rr[0];
#pragma unroll
        for (int k = 0; k < 5; ++k) ins5(u5, rr[1 + k]);
      }
    }
    sp_ += __shfl_xor(sp_, 16, 64);
    sp_ += __shfl_xor(sp_, 32, 64);
    merge5_shfl(u5, 16);
    merge5_shfl(u5, 32);
    if (t == 0) {
      const float st = u5[0] + u5[1] + u5[2] + u5[3] + u5[4];
      contrib += (sp_ - st) * (0.4f / (float)(NB * NN));
    }
#pragma unroll
    for (int msk = 1; msk < 64; msk <<= 1) contrib += __shfl_xor(contrib, msk, 64);
    if (t == 0) atomicAdd(out + 2, contrib);
    return;
  }

  // ---- loss_c (CLIP bi-directional CE) + loss_t (triplet), from scores ----
  __shared__ float s[64 * 65];
  __shared__ float dg[64];
  __shared__ int idl[64];
  for (int i = 0; i < 64; ++i) s[i * 65 + t] = ws[i * 64 + t];
  idl[t] = idx[t];
  __syncthreads();
  dg[t] = s[t * 66];
  __syncthreads();
  const float sc = lscale[0];

  float mR = -FINF, mC = -FINF;
  for (int j = 0; j < 64; ++j) {
    mR = fmaxf(mR, sc * s[t * 65 + j]);
    mC = fmaxf(mC, sc * s[j * 65 + t]);
  }
  float seR = 0.f, seC = 0.f;
  for (int j = 0; j < 64; ++j) {
    seR += expf(sc * s[t * 65 + j] - mR);
    seC += expf(sc * s[j * 65 + t] - mC);
  }
  const float lseR = mR + logf(seR);
  const float lseC = mC + logf(seC);

  const int myid = idl[t];
  const float di = dg[t];
  float ps = 0.f, trow = 0.f, tcol = 0.f, cs = 0.f, ci = 0.f;
  for (int j = 0; j < 64; ++j) {
    const float sv = s[t * 65 + j];
    const float svT = s[j * 65 + t];
    if (idl[j] == myid) {
      ps += 1.f;
      trow += sc * sv - lseR;
      tcol += sc * svT - lseC;
    }
    if (j != t) {
      cs += fmaxf(0.f, 0.1f + sv - di);
      ci += fmaxf(0.f, 0.1f + sv - dg[j]);
    }
  }
  float vc = -(trow + tcol) / ps;
  float vt = cs + ci;
#pragma unroll
  for (int msk = 1; msk < 64; msk <<= 1) {
    vc += __shfl_xor(vc, msk, 64);
    vt += __shfl_xor(vt, msk, 64);
  }
  if (t == 0) {
    out[0] = vc * (0.5f / 64.f);
    out[1] = vt * 0.5f;
  }
}

extern "C" void kernel_launch(void* const* d_in, const int* in_sizes, int n_in,
                              void* d_out, int out_size, void* d_ws, size_t ws_size,
                              hipStream_t stream) {
  const float* patch = (const float*)d_in[0];
  const float* noun  = (const float*)d_in[1];
  const float* gimg  = (const float*)d_in[2];
  const float* gtxt  = (const float*)d_in[3];
  const float* lsc   = (const float*)d_in[4];
  const int*   idx   = (const int*)d_in[5];
  float* out = (float*)d_out;
  float* ws  = (float*)d_ws;

  // out[2] accumulated via atomicAdd across k_final blocks; harness poisons d_out
  hipMemsetAsync(d_out, 0, 3 * sizeof(float), stream);
  k_sim<<<dim3(NBLK1), dim3(256), 0, stream>>>(patch, noun, gimg, gtxt, ws);
  k_final<<<dim3(NB + 1), dim3(64), 0, stream>>>(ws, lsc, idx, out);
}